// Round 1
// baseline (964.177 us; speedup 1.0000x reference)
//
#include <hip/hip_runtime.h>

#define FL_N 1048576
#define FL_C 128
#define FL_ALPHA 0.25f

constexpr int BLOCKS = 1024;
constexpr int TPB    = 256;
constexpr int WAVES_PER_BLOCK = TPB / 64;

// Each wave processes 2 rows (2*128 = 256 floats) per iteration:
// lane L reads float4 at rowpair*256 + L*4 (lanes 0-31 -> row 2r, lanes 32-63 -> row 2r+1).
__global__ __launch_bounds__(TPB) void focal_partial(
    const float* __restrict__ preds,
    const int*   __restrict__ labels,
    float*       __restrict__ partial)
{
    const int tid  = threadIdx.x;
    const int wave = tid >> 6;
    const int lane = tid & 63;
    const int sub  = lane & 31;

    const int wavesTotal = gridDim.x * WAVES_PER_BLOCK;
    const int gwave      = blockIdx.x * WAVES_PER_BLOCK + wave;

    float acc = 0.0f;

    for (int rp = gwave; rp < FL_N / 2; rp += wavesTotal) {
        size_t base = (size_t)rp * (2 * FL_C) + (size_t)lane * 4;
        float4 p = *reinterpret_cast<const float4*>(preds + base);
        int4   l = *reinterpret_cast<const int4*>(labels + base);

        float se = __expf(p.x) + __expf(p.y) + __expf(p.z) + __expf(p.w);
        float ll = p.x * (float)l.x + p.y * (float)l.y
                 + p.z * (float)l.z + p.w * (float)l.w;

        // Reduce within each 32-lane half-wave (one row each); xor masks <= 16
        // never cross the 32-lane boundary.
        #pragma unroll
        for (int m = 16; m >= 1; m >>= 1) {
            se += __shfl_xor(se, m, 64);
            ll += __shfl_xor(ll, m, 64);
        }

        if (sub == 0) {
            float t1 = se;              // sum_j exp(preds[i,j])
            float pp = __expf(ll) / t1; // p = exp(label_logit)/sumexp
            float om = 1.0f - pp;
            // alpha * (1-p)^2 * (t2 + log t1), t2 = -label_logit
            acc += FL_ALPHA * om * om * (__logf(t1) - ll);
        }
    }

    // acc is nonzero only on lanes 0 and 32; full-wave xor reduce sums them.
    #pragma unroll
    for (int m = 32; m >= 1; m >>= 1)
        acc += __shfl_xor(acc, m, 64);

    __shared__ float smem[WAVES_PER_BLOCK];
    if (lane == 0) smem[wave] = acc;
    __syncthreads();
    if (tid == 0) {
        float s = 0.0f;
        #pragma unroll
        for (int w = 0; w < WAVES_PER_BLOCK; ++w) s += smem[w];
        partial[blockIdx.x] = s;   // plain store: no zero-init dependence
    }
}

__global__ __launch_bounds__(256) void focal_final(
    const float* __restrict__ partial,
    float*       __restrict__ out)
{
    const int tid  = threadIdx.x;
    const int wave = tid >> 6;
    const int lane = tid & 63;

    float acc = 0.0f;
    for (int i = tid; i < BLOCKS; i += 256) acc += partial[i];

    #pragma unroll
    for (int m = 32; m >= 1; m >>= 1)
        acc += __shfl_xor(acc, m, 64);

    __shared__ float smem[4];
    if (lane == 0) smem[wave] = acc;
    __syncthreads();
    if (tid == 0) {
        float s = smem[0] + smem[1] + smem[2] + smem[3];
        out[0] = s * (1.0f / (float)FL_N);
    }
}

extern "C" void kernel_launch(void* const* d_in, const int* in_sizes, int n_in,
                              void* d_out, int out_size, void* d_ws, size_t ws_size,
                              hipStream_t stream)
{
    const float* preds  = (const float*)d_in[0];
    const int*   labels = (const int*)d_in[1];
    float*       out    = (float*)d_out;
    float*       part   = (float*)d_ws;   // BLOCKS floats = 4 KiB scratch

    focal_partial<<<BLOCKS, TPB, 0, stream>>>(preds, labels, part);
    focal_final<<<1, 256, 0, stream>>>(part, out);
}

// Round 2
// 927.695 us; speedup vs baseline: 1.0393x; 1.0393x over previous
//
#include <hip/hip_runtime.h>

#define FL_N 1048576
#define FL_C 128
#define FL_ALPHA 0.25f

constexpr int BLOCKS = 2048;
constexpr int TPB    = 256;
constexpr int WAVES_PER_BLOCK = TPB / 64;
constexpr int ROWS_PER_WAVE   = 8;                 // 8 lanes per row
constexpr int ROWBLOCKS       = FL_N / ROWS_PER_WAVE;  // 131072

using f32x4 = __attribute__((ext_vector_type(4))) float;
using i32x4 = __attribute__((ext_vector_type(4))) int;

__device__ __forceinline__ float exp4_sum(f32x4 p) {
    return __expf(p.x) + __expf(p.y) + __expf(p.z) + __expf(p.w);
}
__device__ __forceinline__ float dot4(f32x4 p, i32x4 l) {
    return p.x * (float)l.x + p.y * (float)l.y + p.z * (float)l.z + p.w * (float)l.w;
}

// 8 rows per wave-iteration. Lane L owns row (L>>3) of the row-block and
// float4 chunks (L&7) + 8k, k=0..3 -> float offsets (L&7)*4 + {0,32,64,96}.
// Butterfly over xor masks {1,2,4} reduces within each 8-lane row group.
__global__ __launch_bounds__(TPB) void focal_partial(
    const float* __restrict__ preds,
    const int*   __restrict__ labels,
    float*       __restrict__ partial)
{
    const int tid  = threadIdx.x;
    const int wave = tid >> 6;
    const int lane = tid & 63;

    const int wavesTotal = gridDim.x * WAVES_PER_BLOCK;
    const int gwave      = blockIdx.x * WAVES_PER_BLOCK + wave;

    const int laneOff = (lane >> 3) * FL_C + (lane & 7) * 4;  // float offset in row-block

    float acc = 0.0f;

    for (int rb = gwave; rb < ROWBLOCKS; rb += wavesTotal) {
        size_t base = (size_t)rb * (ROWS_PER_WAVE * FL_C) + laneOff;
        const f32x4* pp = reinterpret_cast<const f32x4*>(preds + base);
        const i32x4* lp = reinterpret_cast<const i32x4*>(labels + base);

        // 8 independent 16B loads (stride 32 floats = 8 float4s within the row)
        f32x4 p0 = __builtin_nontemporal_load(pp + 0);
        f32x4 p1 = __builtin_nontemporal_load(pp + 8);
        f32x4 p2 = __builtin_nontemporal_load(pp + 16);
        f32x4 p3 = __builtin_nontemporal_load(pp + 24);
        i32x4 l0 = __builtin_nontemporal_load(lp + 0);
        i32x4 l1 = __builtin_nontemporal_load(lp + 8);
        i32x4 l2 = __builtin_nontemporal_load(lp + 16);
        i32x4 l3 = __builtin_nontemporal_load(lp + 24);

        float se = exp4_sum(p0) + exp4_sum(p1) + exp4_sum(p2) + exp4_sum(p3);
        float ll = dot4(p0, l0) + dot4(p1, l1) + dot4(p2, l2) + dot4(p3, l3);

        // Reduce within each 8-lane row group (masks < 8 stay in-group).
        #pragma unroll
        for (int m = 4; m >= 1; m >>= 1) {
            se += __shfl_xor(se, m, 64);
            ll += __shfl_xor(ll, m, 64);
        }

        if ((lane & 7) == 0) {
            float t1 = se;               // sum_j exp(preds[i,j])
            float pr = __expf(ll) / t1;  // p
            float om = 1.0f - pr;
            acc += FL_ALPHA * om * om * (__logf(t1) - ll);  // alpha*(1-p)^2*(t2+log t1)
        }
    }

    // acc nonzero only on lanes 0,8,...,56; full-wave butterfly sums them.
    #pragma unroll
    for (int m = 32; m >= 1; m >>= 1)
        acc += __shfl_xor(acc, m, 64);

    __shared__ float smem[WAVES_PER_BLOCK];
    if (lane == 0) smem[wave] = acc;
    __syncthreads();
    if (tid == 0) {
        float s = 0.0f;
        #pragma unroll
        for (int w = 0; w < WAVES_PER_BLOCK; ++w) s += smem[w];
        partial[blockIdx.x] = s;   // plain store: no zero-init dependence
    }
}

__global__ __launch_bounds__(256) void focal_final(
    const float* __restrict__ partial,
    float*       __restrict__ out)
{
    const int tid  = threadIdx.x;
    const int wave = tid >> 6;
    const int lane = tid & 63;

    float acc = 0.0f;
    for (int i = tid; i < BLOCKS; i += 256) acc += partial[i];

    #pragma unroll
    for (int m = 32; m >= 1; m >>= 1)
        acc += __shfl_xor(acc, m, 64);

    __shared__ float smem[4];
    if (lane == 0) smem[wave] = acc;
    __syncthreads();
    if (tid == 0) {
        float s = smem[0] + smem[1] + smem[2] + smem[3];
        out[0] = s * (1.0f / (float)FL_N);
    }
}

extern "C" void kernel_launch(void* const* d_in, const int* in_sizes, int n_in,
                              void* d_out, int out_size, void* d_ws, size_t ws_size,
                              hipStream_t stream)
{
    const float* preds  = (const float*)d_in[0];
    const int*   labels = (const int*)d_in[1];
    float*       out    = (float*)d_out;
    float*       part   = (float*)d_ws;   // BLOCKS floats = 8 KiB scratch

    focal_partial<<<BLOCKS, TPB, 0, stream>>>(preds, labels, part);
    focal_final<<<1, 256, 0, stream>>>(part, out);
}